// Round 9
// baseline (364.297 us; speedup 1.0000x reference)
//
#include <hip/hip_runtime.h>

// Single-head attention, B=4, S=2048, D=1024. fp32 in, fp32 out.
// FAST PATH (ws >= 121 MiB): all-MFMA, bf16 compute, fp32 accum.
// Algebraic fusion: out = diag(1/l) P V Wo = (P @ (x @ (Wv Wo)))/l.
// R15: dispatch-count attack. 8 -> 5 dispatches:
//   1. prep       = conv_f32_bf16 + transp_w4 (block-range partition)
//   2. WvoT gemm  (old 128^2 engine, unchanged)
//   3. QKU        = gemm8<0,4> (768 wgs) + pack_mask tail (1024 wgs).
//      pm lives in the WoT slot -- dead after dispatch 2 read it.
//   4. score      = gemm8<1,2> (256 wgs) + transp-U tail (1024 wgs, 2
//      64x64 tiles per 512-thr block, LDS reused from Abuf).
//   5. PVout      = gemm8<2,4> (256 wgs).
// Engines: R12-proven TILE8 4-phase counted-vmcnt schedule for BOTH WM
// (R14's TILE2 was neutral -> reverted). T1 bijective XCD swizzle over the
// gemm prefix of each 1D grid. Bit-packed mask epilogue (R12).
// FALLBACK (small ws): round-4 proven VALU pipeline (48 MB).

#define DM 1024
#define SQ 2048
#define NB 4
typedef unsigned short U16;
typedef unsigned long long U64;
typedef short bhalf8 __attribute__((ext_vector_type(8)));
typedef float f32x4 __attribute__((ext_vector_type(4)));

__device__ inline U16 f2bf(float f) {
  unsigned int u = __float_as_uint(f);
  u += 0x7FFFu + ((u >> 16) & 1u);  // RNE
  return (U16)(u >> 16);
}
__device__ inline float2 bfp2(unsigned int u) {
  float2 r;
  r.x = __uint_as_float(u << 16);
  r.y = __uint_as_float(u & 0xffff0000u);
  return r;
}
__device__ inline unsigned int packbf(float a, float b) {
  return (unsigned int)f2bf(a) | ((unsigned int)f2bf(b) << 16);
}

// Direct global->LDS DMA, 16 B per lane. LDS dest = m0 (wave-uniform) +
// lane*16; global source is per-lane (this is how the swizzle is applied).
__device__ __forceinline__ void gload16(const U16* g, const U16* l) {
  unsigned int m0v =
      (unsigned int)__builtin_amdgcn_readfirstlane((int)(unsigned long long)l);
  asm volatile("s_mov_b32 m0, %0\n\t"
               "global_load_lds_dwordx4 %1, off"
               :
               : "s"(m0v), "v"(g)
               : "memory");
}

__device__ inline void ldcvt16(const float* p, U16* d) {
#pragma unroll
  for (int i = 0; i < 4; ++i) {
    float4 f = *(const float4*)(p + i * 4);
    d[i * 4 + 0] = f2bf(f.x); d[i * 4 + 1] = f2bf(f.y);
    d[i * 4 + 2] = f2bf(f.z); d[i * 4 + 3] = f2bf(f.w);
  }
}
__device__ inline void ldcvt16(const U16* p, U16* d) {
  uint4 a = *(const uint4*)p;
  uint4 b = *(const uint4*)(p + 8);
  *(uint4*)d = a;
  *(uint4*)(d + 8) = b;
}

// ---------------------------------------------------------------- fast path --
// prep: blocks [0,4096) = x fp32->bf16 conv (+rs zero);
//       blocks [4096,5120) = transp_w4 (z = (blk-4096)>>8).
__global__ __launch_bounds__(256) void prep(
    const float* __restrict__ x, U16* __restrict__ x16, float* __restrict__ rs,
    const float* __restrict__ Wq, const float* __restrict__ Wk,
    const float* __restrict__ Wo, const float* __restrict__ Wv,
    U16* __restrict__ WT, U16* __restrict__ WoT, U16* __restrict__ Wv16) {
  __shared__ U16 tile[64][72];
  const int t = threadIdx.x;
  if (blockIdx.x < 4096) {  // conv
    int idx = blockIdx.x * 256 + t;
    if (idx < NB * SQ) rs[idx] = 0.f;
    int i = idx * 8;
    float4 a = *(const float4*)(x + i);
    float4 b = *(const float4*)(x + i + 4);
    uint4 w;
    w.x = packbf(a.x, a.y); w.y = packbf(a.z, a.w);
    w.z = packbf(b.x, b.y); w.w = packbf(b.z, b.w);
    *(uint4*)(x16 + i) = w;
    return;
  }
  // transp_w4: z=0 Wq^T->WT; z=1 Wk^T->WT+WE; z=2 Wo^T->WoT; z=3 Wv conv.
  const int tw = blockIdx.x - 4096;
  const int z = tw >> 8;
  const int rem = tw & 255;
  const int r0 = (rem >> 4) * 64, c0 = (rem & 15) * 64;
  const int tr = t >> 2, tc = (t & 3) * 16;
  if (z == 3) {  // straight conv of Wv
    U16 vals[16];
    ldcvt16(Wv + (size_t)(r0 + tr) * DM + c0 + tc, vals);
    U16* op = Wv16 + (size_t)(r0 + tr) * DM + c0 + tc;
    *(uint4*)op = *(uint4*)&vals[0];
    *(uint4*)(op + 8) = *(uint4*)&vals[8];
    return;
  }
  const float* src = (z == 0) ? Wq : (z == 1) ? Wk : Wo;
  U16* d = (z == 2) ? WoT : WT + (size_t)z * DM * DM;
  ldcvt16(src + (size_t)(r0 + tr) * DM + c0 + tc, &tile[tr][tc]);
  __syncthreads();
  U16 vals[16];
#pragma unroll
  for (int m = 0; m < 16; ++m) vals[m] = tile[tc + m][tr];
  U16* op = d + (size_t)(c0 + tr) * DM + r0 + tc;
  *(uint4*)op = *(uint4*)&vals[0];
  *(uint4*)(op + 8) = *(uint4*)&vals[8];
}

// ---- old 128x128 engine (kept for the small WvoT gemm only) ----------------
template <int EP>
__global__ __launch_bounds__(256) void gemm_mfma(
    const U16* __restrict__ A, const U16* __restrict__ B, void* __restrict__ Cv,
    int M, int N, int K, long long sA, long long sB, long long sC,
    const int* __restrict__ mask, float* __restrict__ rowsum, float scale) {
  __shared__ U16 As[128 * 72];
  __shared__ U16 Bs[128 * 72];
  const int t = threadIdx.x;
  const int lane = t & 63, wave = t >> 6;
  const int wm = wave >> 1, wn = wave & 1;
  const int q = lane >> 4, ln = lane & 15;
  const int z = blockIdx.z;
  const int m0 = blockIdx.y * 128, n0 = blockIdx.x * 128;
  A += (size_t)z * sA;
  B += (size_t)z * sB;

  f32x4 acc[4][4] = {};

  const int srow = t >> 3;
  const int scol = (t & 7) * 8;

  for (int k0 = 0; k0 < K; k0 += 64) {
    const U16* ga = A + (size_t)(m0 + srow) * K + k0 + scol;
    const U16* gb = B + (size_t)(n0 + srow) * K + k0 + scol;
#pragma unroll
    for (int it = 0; it < 4; ++it) {
      uint4 va = *(const uint4*)(ga + (size_t)it * 32 * K);
      uint4 vb = *(const uint4*)(gb + (size_t)it * 32 * K);
      *(uint4*)&As[(it * 32 + srow) * 72 + scol] = va;
      *(uint4*)&Bs[(it * 32 + srow) * 72 + scol] = vb;
    }
    __syncthreads();
#pragma unroll
    for (int kk = 0; kk < 64; kk += 32) {
      bhalf8 af[4], bg[4];
#pragma unroll
      for (int i = 0; i < 4; ++i) {
        af[i] = *(const bhalf8*)&As[(wm * 64 + i * 16 + ln) * 72 + kk + q * 8];
        bg[i] = *(const bhalf8*)&Bs[(wn * 64 + i * 16 + ln) * 72 + kk + q * 8];
      }
#pragma unroll
      for (int i = 0; i < 4; ++i)
#pragma unroll
        for (int j = 0; j < 4; ++j)
          acc[i][j] = __builtin_amdgcn_mfma_f32_16x16x32_bf16(af[i], bg[j], acc[i][j], 0, 0, 0);
    }
    __syncthreads();
  }

#pragma unroll
  for (int i = 0; i < 4; ++i) {
#pragma unroll
    for (int r = 0; r < 4; ++r) {
      const int rr = m0 + wm * 64 + i * 16 + q * 4 + r;
      float linv = 0.f;
      if constexpr (EP == 2) linv = 1.0f / (rowsum[(size_t)z * M + rr] + 1e-30f);
#pragma unroll
      for (int j = 0; j < 4; ++j) {
        const int c = n0 + wn * 64 + j * 16 + ln;
        float v = acc[i][j][r];
        if constexpr (EP == 0) {
          ((U16*)Cv)[(size_t)z * sC + (size_t)rr * N + c] = f2bf(v);
        } else {
          ((float*)Cv)[(size_t)z * sC + (size_t)rr * N + c] = v * linv;
        }
      }
    }
  }
}

// ---- R12 4-phase counted-vmcnt engine (QKU / score / PVout) ----------------
// C = A @ B'^T : A[M][K] bf16, B'[N][K] bf16, fp32 accum. BM=256, BK=64,
// 512 thr / 8 waves. WM=2 -> BN=256 (2Mx4N waves, per-wave 128x64, acc[8][4]);
// WM=4 -> BN=128 (4Mx2N waves, per-wave 64x64, acc[4][4]).
// 1D grid: blocks [0, gx*gy*gz) = gemm (T1 bijective XCD swizzle over this
// prefix); blocks beyond = tail work: EP==0 pack_mask (taux=mask int32,
// taux2=pm u64), EP==1 transp-U (taux=U src, taux2=UT dst; 2 tiles/block).
// LDS: Abuf[2][256*64] + Bbuf[2][BN*64]; phys-remapped contiguous slots:
// A phys = mh*128 + wm*(MR/2) + im*16 + ln; B phys = nh*HB + wn*32 + jn*16+ln.
// XOR-swizzle chunk^(physrow&7) on DMA *source* addr and ds_read addr.
// Per K-tile: 4 phases = C-quadrants; stage plan P0: BO[t+1], P1: AY[t+1],
// P2: AX[t+2], P3: BE[t+2]. PUBLICATION RULE: vmcnt is per-wave; a slot is
// readable only after {all waves WAITV(N) covering it} + barrier, one phase
// earlier. Per-tile issue {b,2,2,b} makes N uniform = 4+2b (b=CB). Never 0
// in-loop. EP=1: P = exp(mask(acc*scale)) via bit-packed mask + rowsum atomics.
template <int EP, int WM>
__global__ __launch_bounds__(512, 1) void gemm8(
    const U16* __restrict__ A, const U16* __restrict__ B, void* __restrict__ Cv,
    int M, int N, int K, long long sA, long long sB, long long sC,
    const U64* __restrict__ pmask, float* __restrict__ rowsum, float scale,
    int gx, int gy, int gz,
    const void* __restrict__ taux, void* __restrict__ taux2) {
  constexpr int WN = 8 / WM;      // waves along N: 4 or 2
  constexpr int BN = WN * 64;     // 256 or 128
  constexpr int MR = 256 / WM;    // per-wave M rows: 128 or 64
  constexpr int FM = MR / 16;     // m-frags per wave: 8 or 4
  constexpr int IMq = FM / 2;     // m-frags per quadrant: 4 or 2
  constexpr int HB = BN / 2;      // B-half rows: 128 or 64
  constexpr int CB = HB / 64;     // stage calls per B-half: 2 or 1
  constexpr int VW = 4 + 2 * CB;  // uniform counted vmcnt (8 or 6)
  __shared__ __attribute__((aligned(16))) U16 Abuf[2][256 * 64];
  __shared__ __attribute__((aligned(16))) U16 Bbuf[2][BN * 64];
  const int t = threadIdx.x;
  const int nwg = gx * gy * gz;

  if ((int)blockIdx.x >= nwg) {  // ------- tail blocks -------
    const int tb = (int)blockIdx.x - nwg;
    if constexpr (EP == 0) {  // pack_mask: 1024 blocks x 8 waves
      const int lane = t & 63;
      const int wv = tb * 8 + (t >> 6);
      const int* msk = (const int*)taux;
      U64* pmo = (U64*)taux2;
#pragma unroll 4
      for (int i = 0; i < 32; ++i) {
        size_t g = (size_t)wv * 32 + i;
        U64 bb = __ballot(msk[g * 64 + lane] != 0);
        if (lane == 0) pmo[g] = bb;
      }
    } else if constexpr (EP == 1) {  // transp-U: 1024 blocks x 2 tiles
      const int half = t >> 8;
      const int tl = t & 255;
      const int tid = tb * 2 + half;      // [0, 2048)
      const int z = tid >> 9;             // NB
      const int rem2 = tid & 511;         // 32 x 16
      const int r0 = (rem2 >> 4) * 64;    // over SQ
      const int c0 = (rem2 & 15) * 64;    // over DM
      const U16* src = (const U16*)taux + (size_t)z * SQ * DM;
      U16* dst = (U16*)taux2 + (size_t)z * SQ * DM;
      const int tr = tl >> 2, tc = (tl & 3) * 16;
      U16* tile = &Abuf[0][0] + half * (64 * 72);
      ldcvt16(src + (size_t)(r0 + tr) * DM + c0 + tc, &tile[tr * 72 + tc]);
      __syncthreads();
      U16 vals[16];
#pragma unroll
      for (int m = 0; m < 16; ++m) vals[m] = tile[(tc + m) * 72 + tr];
      U16* op = dst + (size_t)(c0 + tr) * SQ + r0 + tc;
      *(uint4*)op = *(uint4*)&vals[0];
      *(uint4*)(op + 8) = *(uint4*)&vals[8];
    }
    return;
  }

  const int lane = t & 63, wave = t >> 6;
  const int wm = wave / WN, wn = wave % WN;
  const int q = lane >> 4, ln = lane & 15;
  const int lxor = ln & 7;

  // T1: bijective chunked XCD swizzle over the gemm prefix (nwg % 8 == 0).
  int lin = blockIdx.x;
  const int cpx = nwg >> 3;
  lin = (lin & 7) * cpx + (lin >> 3);
  const int bz = lin / (gx * gy);
  const int rem = lin - bz * gx * gy;
  const int by = rem / gx, bx = rem - by * gx;

  const int m0 = by * 256, n0 = bx * BN;
  const U16* Abase = A + (size_t)bz * sA + (size_t)m0 * K;
  const U16* Bbase = B + (size_t)bz * sB + (size_t)n0 * K;

  // staging geometry: each stage call covers 64 contiguous PHYS rows via
  // 8 waves x 8 rows; lane l -> phys row pr = wave*8 + (l>>3), phys chunk
  // (l&7). Source chunk is inverse-swizzled: (l&7) ^ (pr&7).
  const int pr = wave * 8 + (lane >> 3);
  const int cchunk = (((lane & 7) ^ ((lane >> 3) & 7)) << 3);
  int la[4];
#pragma unroll
  for (int c = 0; c < 4; ++c) {  // logical A row for phys chunk c
    int p = c * 64 + pr;
    int mh = p >> 7, q64 = p & 127;
    la[c] = (q64 / (MR / 2)) * MR + mh * (MR / 2) + (q64 % (MR / 2));
  }
  int lb[4] = {0, 0, 0, 0};
#pragma unroll
  for (int c = 0; c < 2 * CB; ++c) {  // logical B row for phys chunk c
    int p = c * 64 + pr;
    int nh = p / HB, rem2 = p % HB;
    lb[c] = (rem2 >> 5) * 64 + nh * 32 + (rem2 & 31);
  }
  const U16* gA0 = Abase + (size_t)la[0] * K + cchunk;
  const U16* gA1 = Abase + (size_t)la[1] * K + cchunk;
  const U16* gA2 = Abase + (size_t)la[2] * K + cchunk;
  const U16* gA3 = Abase + (size_t)la[3] * K + cchunk;
  const U16* gB0 = Bbase + (size_t)lb[0] * K + cchunk;
  const U16* gB1 = (CB == 2) ? Bbase + (size_t)lb[1] * K + cchunk : gB0;
  const U16* gB2 = Bbase + (size_t)lb[CB] * K + cchunk;
  const U16* gB3 = (CB == 2) ? Bbase + (size_t)lb[3] * K + cchunk : gB2;
  const int wofs = wave * 8 * 64;  // wave's LDS offset within a 64-row call

#define ST_AX(bi, ko) { gload16(gA0 + (ko), &Abuf[bi][0 * 64 + wofs]);         \
                        gload16(gA1 + (ko), &Abuf[bi][64 * 64 + wofs]); }
#define ST_AY(bi, ko) { gload16(gA2 + (ko), &Abuf[bi][128 * 64 + wofs]);       \
                        gload16(gA3 + (ko), &Abuf[bi][192 * 64 + wofs]); }
#define ST_BE(bi, ko) { gload16(gB0 + (ko), &Bbuf[bi][0 * 64 + wofs]);         \
                        if (CB == 2) gload16(gB1 + (ko), &Bbuf[bi][64 * 64 + wofs]); }
#define ST_BO(bi, ko) { gload16(gB2 + (ko), &Bbuf[bi][HB * 64 + wofs]);        \
                        if (CB == 2) gload16(gB3 + (ko), &Bbuf[bi][(HB + 64) * 64 + wofs]); }

  f32x4 acc[FM][4] = {};
  bhalf8 af[IMq][2], bgE[2][2], bgO[2][2];

#define LDA(bi, mh) {                                                          \
  _Pragma("unroll") for (int im = 0; im < IMq; ++im)                           \
  _Pragma("unroll") for (int kx = 0; kx < 2; ++kx)                             \
    af[im][kx] = *(const bhalf8*)&Abuf[bi][                                    \
        ((mh) * 128 + wm * (MR / 2) + im * 16 + ln) * 64 +                     \
        (((kx * 4 + q) ^ lxor) << 3)]; }
#define LDB(bi, nh, BG) {                                                      \
  _Pragma("unroll") for (int jn = 0; jn < 2; ++jn)                             \
  _Pragma("unroll") for (int kx = 0; kx < 2; ++kx)                             \
    BG[jn][kx] = *(const bhalf8*)&Bbuf[bi][                                    \
        ((nh) * HB + wn * 32 + jn * 16 + ln) * 64 +                            \
        (((kx * 4 + q) ^ lxor) << 3)]; }
#define MQ(mh, nh, BG) {                                                       \
  __builtin_amdgcn_s_setprio(1);                                               \
  _Pragma("unroll") for (int im = 0; im < IMq; ++im)                           \
  _Pragma("unroll") for (int jn = 0; jn < 2; ++jn)                             \
  _Pragma("unroll") for (int kx = 0; kx < 2; ++kx)                             \
    acc[(mh) * IMq + im][(nh) * 2 + jn] =                                      \
        __builtin_amdgcn_mfma_f32_16x16x32_bf16(                               \
            af[im][kx], BG[jn][kx], acc[(mh) * IMq + im][(nh) * 2 + jn],       \
            0, 0, 0);                                                          \
  __builtin_amdgcn_s_setprio(0); }
#define WAITV(n) asm volatile("s_waitcnt vmcnt(%0)" :: "i"(n) : "memory")
#define BAR() __builtin_amdgcn_s_barrier()
#define LGKM0() asm volatile("s_waitcnt lgkmcnt(0)" ::: "memory")

#define TILE8(bi, nbi, kA, kB)                                                 \
  {                                                                            \
    ST_BO(nbi, kA); WAITV(VW);                                                 \
    LDA(bi, 0); LDB(bi, 0, bgE);                                               \
    BAR(); LGKM0(); MQ(0, 0, bgE); BAR();                                      \
    ST_AY(nbi, kA); WAITV(VW);                                                 \
    LDB(bi, 1, bgO);                                                           \
    BAR(); LGKM0(); MQ(0, 1, bgO); BAR();                                      \
    ST_AX(bi, kB); WAITV(VW);                                                  \
    LDA(bi, 1);                                                                \
    BAR(); LGKM0(); MQ(1, 0, bgE); BAR();                                      \
    ST_BE(bi, kB); WAITV(VW);                                                  \
    BAR(); LGKM0(); MQ(1, 1, bgO); BAR();                                      \
  }

  const int NT = K >> 6;  // even (>= 16) for all shapes used here
  // prologue: AX[0], BE[0], BO[0], AY[0], AX[1], BE[1]; publish AX[0]/BE[0]
  // (oldest 2+b loads) via WAITV(VW)+BAR.
  ST_AX(0, 0); ST_BE(0, 0); ST_BO(0, 0); ST_AY(0, 0);
  ST_AX(1, 64); ST_BE(1, 64);
  WAITV(VW); BAR();
  for (int tt = 0; tt < NT; tt += 2) {
    const int k1 = (tt + 1) * 64;                      // tile tt+1 (valid)
    const int k2 = (tt + 2 < NT) ? (tt + 2) * 64 : 0;  // tile tt+2 (clamped)
    const int k3 = (tt + 3 < NT) ? (tt + 3) * 64 : 0;  // tile tt+3 (clamped)
    TILE8(0, 1, k1, k2);
    TILE8(1, 0, k2, k3);
  }
  WAITV(0);

#undef ST_AX
#undef ST_AY
#undef ST_BE
#undef ST_BO
#undef LDA
#undef LDB
#undef MQ
#undef WAITV
#undef BAR
#undef LGKM0
#undef TILE8

  // epilogue
#pragma unroll
  for (int i = 0; i < FM; ++i) {
#pragma unroll
    for (int r = 0; r < 4; ++r) {
      const int rr = m0 + wm * MR + i * 16 + q * 4 + r;
      float linv = 0.f;
      if constexpr (EP == 2) linv = 1.0f / (rowsum[(size_t)bz * M + rr] + 1e-30f);
      U64 m64 = 0;
      if constexpr (EP == 1)
        m64 = pmask[((size_t)bz * M + rr) * (N >> 6) + (n0 >> 6) + wn];
      float psum = 0.f;
#pragma unroll
      for (int j = 0; j < 4; ++j) {
        const int c = n0 + wn * 64 + j * 16 + ln;
        float v = acc[i][j][r];
        if constexpr (EP == 0) {
          ((U16*)Cv)[(size_t)bz * sC + (size_t)rr * N + c] = f2bf(v);
        } else if constexpr (EP == 1) {
          int mk = (int)((m64 >> (j * 16 + ln)) & 1ull);
          float p = mk ? __expf(v * scale) : 0.f;
          U16 pb = f2bf(p);
          ((U16*)Cv)[(size_t)bz * sC + (size_t)rr * N + c] = pb;
          psum += __uint_as_float((unsigned int)pb << 16);  // sum rounded P
        } else {
          ((float*)Cv)[(size_t)bz * sC + (size_t)rr * N + c] = v * linv;
        }
      }
      if constexpr (EP == 1) {
#pragma unroll
        for (int off = 8; off > 0; off >>= 1) psum += __shfl_xor(psum, off, 64);
        if (ln == 0) atomicAdd(&rowsum[(size_t)bz * M + rr], psum);
      }
    }
  }
}

// ------------------------------------------------------------ fallback path --
__device__ inline float4 load4(const float* p) { return *(const float4*)p; }
__device__ inline float4 load4(const U16* p) {
  uint2 w = *(const uint2*)p;
  float2 f0 = bfp2(w.x), f1 = bfp2(w.y);
  return make_float4(f0.x, f0.y, f1.x, f1.y);
}
__device__ inline void store4(float* p, float a, float b, float c, float d) {
  *(float4*)p = make_float4(a, b, c, d);
}
__device__ inline void store4(U16* p, float a, float b, float c, float d) {
  uint2 w;
  w.x = packbf(a, b);
  w.y = packbf(c, d);
  *(uint2*)p = w;
}
template <typename TA, typename TB, typename TC>
__global__ __launch_bounds__(256) void gemm_t(
    const TA* __restrict__ A, const TB* __restrict__ B,
    TC* __restrict__ C, int M, int N, int K) {
  __shared__ float As[16][64];
  __shared__ float Bs[16][64];
  const int t = threadIdx.x;
  const int tx = t & 15, ty = t >> 4;
  const int m0 = blockIdx.y * 64;
  const int n0 = blockIdx.x * 64;
  const int arow = t >> 2, akq = (t & 3) * 4;
  const int brow = t >> 4, bcg = (t & 15) * 4;
  float acc[4][4] = {};
  for (int k0 = 0; k0 < K; k0 += 16) {
    {
      float4 f = load4(A + (size_t)(m0 + arow) * K + k0 + akq);
      As[akq + 0][arow] = f.x; As[akq + 1][arow] = f.y;
      As[akq + 2][arow] = f.z; As[akq + 3][arow] = f.w;
    }
    {
      float4 f = load4(B + (size_t)(k0 + brow) * N + n0 + bcg);
      *(float4*)&Bs[brow][bcg] = f;
    }
    __syncthreads();
#pragma unroll
    for (int kk = 0; kk < 16; ++kk) {
      float4 a = *(const float4*)&As[kk][ty * 4];
      float4 b = *(const float4*)&Bs[kk][tx * 4];
      float av[4] = {a.x, a.y, a.z, a.w};
      float bv[4] = {b.x, b.y, b.z, b.w};
#pragma unroll
      for (int i = 0; i < 4; ++i)
#pragma unroll
        for (int j = 0; j < 4; ++j) acc[i][j] += av[i] * bv[j];
    }
    __syncthreads();
  }
#pragma unroll
  for (int i = 0; i < 4; ++i)
    store4(&C[(size_t)(m0 + ty * 4 + i) * N + n0 + tx * 4],
           acc[i][0], acc[i][1], acc[i][2], acc[i][3]);
}
__global__ __launch_bounds__(256) void flash_wave(
    const U16* __restrict__ Q, const U16* __restrict__ Kd,
    const U16* __restrict__ V, const int* __restrict__ mask,
    U16* __restrict__ O) {
  __shared__ float q_s[4][DM];
  const int t = threadIdx.x;
  const int w = t >> 6;
  const int lane = t & 63;
  const int row = blockIdx.x * 4 + w;
  const int b = row >> 11;
  const size_t bo = (size_t)b * SQ * DM;
  const size_t mrow0 = (size_t)row * SQ;
  {
    const U16* qp = Q + (size_t)row * DM + lane * 16;
    uint4 w0 = *(const uint4*)qp;
    uint4 w1 = *(const uint4*)(qp + 8);
    float* dst = &q_s[w][lane * 16];
    float2 f;
    f = bfp2(w0.x); dst[0] = f.x;  dst[1] = f.y;
    f = bfp2(w0.y); dst[2] = f.x;  dst[3] = f.y;
    f = bfp2(w0.z); dst[4] = f.x;  dst[5] = f.y;
    f = bfp2(w0.w); dst[6] = f.x;  dst[7] = f.y;
    f = bfp2(w1.x); dst[8] = f.x;  dst[9] = f.y;
    f = bfp2(w1.y); dst[10] = f.x; dst[11] = f.y;
    f = bfp2(w1.z); dst[12] = f.x; dst[13] = f.y;
    f = bfp2(w1.w); dst[14] = f.x; dst[15] = f.y;
  }
  __syncthreads();
  float m = -3.0e38f, l = 0.f;
  float o[16] = {};
  const int dbase = lane * 16;
  const float* qrow = q_s[w];
  for (int j0 = 0; j0 < SQ; j0 += 64) {
    float s;
    {
      const U16* kp = Kd + bo + (size_t)(j0 + lane) * DM;
      float acc = 0.f;
      for (int d = 0; d < DM; d += 8) {
        uint4 kw = *(const uint4*)(kp + d);
        float2 a0 = bfp2(kw.x), a1 = bfp2(kw.y), a2 = bfp2(kw.z), a3 = bfp2(kw.w);
        acc += qrow[d] * a0.x + qrow[d + 1] * a0.y + qrow[d + 2] * a1.x +
               qrow[d + 3] * a1.y + qrow[d + 4] * a2.x + qrow[d + 5] * a2.y +
               qrow[d + 6] * a3.x + qrow[d + 7] * a3.y;
      }
      s = acc * 0.03125f;
      if (mask[mrow0 + j0 + lane] == 0) s = -1e10f;
    }
    float ms = s;
#pragma unroll
    for (int off = 32; off > 0; off >>= 1) ms = fmaxf(ms, __shfl_xor(ms, off, 64));
    float mn = fmaxf(m, ms);
    float alpha = __expf(m - mn);
    float p = __expf(s - mn);
    float ps = p;
#pragma unroll
    for (int off = 32; off > 0; off >>= 1) ps += __shfl_xor(ps, off, 64);
    l = l * alpha + ps;
    m = mn;
#pragma unroll
    for (int k = 0; k < 16; ++k) o[k] *= alpha;
    const U16* vp = V + bo + (size_t)j0 * DM + dbase;
    for (int j = 0; j < 64; ++j) {
      float pj = __shfl(p, j, 64);
      uint4 v0 = *(const uint4*)(vp + (size_t)j * DM);
      uint4 v1 = *(const uint4*)(vp + (size_t)j * DM + 8);
      float2 f0 = bfp2(v0.x), f1 = bfp2(v0.y), f2 = bfp2(v0.z), f3 = bfp2(v0.w);
      float2 g0 = bfp2(v1.x), g1 = bfp2(v1.y), g2 = bfp2(v1.z), g3 = bfp2(v1.w);
      o[0] += pj * f0.x;  o[1] += pj * f0.y;  o[2] += pj * f1.x;  o[3] += pj * f1.y;
      o[4] += pj * f2.x;  o[5] += pj * f2.y;  o[6] += pj * f3.x;  o[7] += pj * f3.y;
      o[8] += pj * g0.x;  o[9] += pj * g0.y;  o[10] += pj * g1.x; o[11] += pj * g1.y;
      o[12] += pj * g2.x; o[13] += pj * g2.y; o[14] += pj * g3.x; o[15] += pj * g3.y;
    }
  }
  float linv = (l > 0.f) ? (1.0f / l) : 0.f;
  U16* op = O + (size_t)row * DM + dbase;
  uint4 r0, r1;
  r0.x = packbf(o[0] * linv, o[1] * linv);
  r0.y = packbf(o[2] * linv, o[3] * linv);
  r0.z = packbf(o[4] * linv, o[5] * linv);
  r0.w = packbf(o[6] * linv, o[7] * linv);
  r1.x = packbf(o[8] * linv, o[9] * linv);
  r1.y = packbf(o[10] * linv, o[11] * linv);
  r1.z = packbf(o[12] * linv, o[13] * linv);
  r1.w = packbf(o[14] * linv, o[15] * linv);
  *(uint4*)op = r0;
  *(uint4*)(op + 8) = r1;
}

extern "C" void kernel_launch(void* const* d_in, const int* in_sizes, int n_in,
                              void* d_out, int out_size, void* d_ws, size_t ws_size,
                              hipStream_t stream) {
  const float* x  = (const float*)d_in[0];
  const int* mask = (const int*)d_in[1];
  const float* Wq = (const float*)d_in[2];
  const float* Wk = (const float*)d_in[3];
  const float* Wv = (const float*)d_in[4];
  const float* Wo = (const float*)d_in[5];
  float* out = (float*)d_out;

  const size_t MB = 1u << 20;
  const size_t E = (size_t)NB * SQ * DM;  // 8388608
  const size_t WE = (size_t)DM * DM;      // 1048576

  if (ws_size >= 121 * MB) {
    // -------- fast MFMA path (5 dispatches) --------
    char* ws = (char*)d_ws;
    U16* WT   = (U16*)ws;               // slot0 Wq^T, slot1 Wk^T, slot2 Wvo^T
    U16* WoT  = (U16*)(ws + 6 * MB);    // Wo^T (2 MiB; becomes pmask after WvoT gemm)
    U64* pm   = (U64*)(ws + 6 * MB);    // bit-packed mask (2 MiB)
    U16* x16  = (U16*)(ws + 8 * MB);
    U16* Q16  = (U16*)(ws + 24 * MB);   // Q,K,U contiguous at stride E elems
    U16* K16  = (U16*)(ws + 40 * MB);
    U16* U16b = (U16*)(ws + 56 * MB);   // U = x @ (Wv Wo) = V Wo
    U16* Wv16 = (U16*)(ws + 72 * MB);   // Wv bf16 (2 MiB, dead after WvoT gemm)
    U16* UT16 = (U16*)(ws + 72 * MB);   // U^T per batch (16 MiB, written later)
    U16* P16  = (U16*)(ws + 88 * MB);   // 32 MiB
    float* rs = (float*)(ws + 120 * MB);

    // 1: conv + transp_w4 merged.
    prep<<<dim3(5120), 256, 0, stream>>>(x, x16, rs, Wq, Wk, Wo, Wv, WT, WoT, Wv16);

    // 2: Wvo^T[e][d] = sum_f WoT[e][f] * Wv[d][f]  (2.1 GF, 64 wgs).
    gemm_mfma<0><<<dim3(DM / 128, DM / 128, 1), 256, 0, stream>>>(
        WoT, Wv16, WT + 2 * WE, DM, DM, DM, 0, 0, 0, nullptr, nullptr, 0.f);

    // 3: fused Q/K/U (768 gemm wgs, WM=4) + pack_mask tail (1024 wgs).
    //    pm overwrites the WoT slot -- dead after dispatch 2.
    gemm8<0, 4><<<dim3(768 + 1024), 512, 0, stream>>>(
        x16, WT, Q16, NB * SQ, DM, DM,
        0, (long long)WE, (long long)E, nullptr, nullptr, 0.f,
        DM / 128, (NB * SQ) / 256, 3, mask, pm);

    // 4: score P = exp(mask(Q@K^T/32)) + rowsum atomics (256 gemm wgs, WM=2)
    //    + transp-U tail (1024 wgs -> UT16).
    gemm8<1, 2><<<dim3(256 + 1024), 512, 0, stream>>>(
        Q16, K16, P16, SQ, SQ, DM,
        (long long)SQ * DM, (long long)SQ * DM, (long long)SQ * SQ,
        pm, rs, 0.03125f,
        SQ / 256, SQ / 256, NB, U16b, UT16);

    // 5: out = (P @ UT^T) / rowsum, fp32 direct to d_out (256 wgs, WM=4).
    gemm8<2, 4><<<dim3(256), 512, 0, stream>>>(
        P16, UT16, out, SQ, DM, SQ,
        (long long)SQ * SQ, (long long)DM * SQ, (long long)SQ * DM,
        nullptr, rs, 0.f,
        DM / 128, SQ / 256, NB, nullptr, nullptr);
  } else {
    // -------- round-4 proven fallback (48 MB) --------
    U16* Kw = (U16*)d_ws;
    U16* Vw = Kw + E;
    U16* Qw = Vw + E;
    U16* Ow = Qw;
    dim3 blk(256);
    dim3 gg(DM / 64, (NB * SQ) / 64);
    gemm_t<float, float, U16><<<gg, blk, 0, stream>>>(x, Wk, Kw, NB * SQ, DM, DM);
    gemm_t<float, float, U16><<<gg, blk, 0, stream>>>(x, Wv, Vw, NB * SQ, DM, DM);
    gemm_t<float, float, U16><<<gg, blk, 0, stream>>>(x, Wq, Qw, NB * SQ, DM, DM);
    flash_wave<<<dim3((NB * SQ) / 4), blk, 0, stream>>>(Qw, Kw, Vw, mask, Ow);
    gemm_t<U16, float, float><<<gg, blk, 0, stream>>>(Ow, Wo, out, NB * SQ, DM, DM);
  }
}

// Round 11
// 323.090 us; speedup vs baseline: 1.1275x; 1.1275x over previous
//
#include <hip/hip_runtime.h>

// Single-head attention, B=4, S=2048, D=1024. fp32 in, fp32 out.
// FAST PATH (ws >= 121 MiB): all-MFMA, bf16 compute, fp32 accum.
// Algebraic fusion: out = diag(1/l) P V Wo = (P @ (x @ (Wv Wo)))/l.
// R16 (resubmit; R10's bench was an infra failure, kernel never measured):
// revert R15's tail-block merges (they serialized: tails inherited the
// gemm's 512-thr/1-block-per-CU footprint -> +4 chip rounds, 66->136 us).
// Keep R12's proven engines/dispatch structure, merge ONLY matching-
// occupancy streaming kernels:
//   1. prep        = conv_f32_bf16 + transp_w4 (256-thr, block partition)
//   2. WvoT gemm   (old 128^2 engine, 64 wgs)
//   3. QKU         = gemm8<0,4>, dim3(8,32,3), pure (R12 form)
//   4. transp_pack = transp-U + pack_mask (256-thr; grid z-partition;
//      pm overwrites WoT slot, dead after dispatch 2)
//   5. score       = gemm8<1,2>, dim3(8,8,4), bit-packed mask epilogue
//   6. PVout       = gemm8<2,4>, dim3(8,8,4)
// Engines: R12 TILE8 4-phase counted-vmcnt schedule, T1 bijective XCD
// swizzle, XOR-swizzled LDS (conflicts 0), global_load_lds staging.
// FALLBACK (small ws): round-4 proven VALU pipeline (48 MB).

#define DM 1024
#define SQ 2048
#define NB 4
typedef unsigned short U16;
typedef unsigned long long U64;
typedef short bhalf8 __attribute__((ext_vector_type(8)));
typedef float f32x4 __attribute__((ext_vector_type(4)));

__device__ inline U16 f2bf(float f) {
  unsigned int u = __float_as_uint(f);
  u += 0x7FFFu + ((u >> 16) & 1u);  // RNE
  return (U16)(u >> 16);
}
__device__ inline float2 bfp2(unsigned int u) {
  float2 r;
  r.x = __uint_as_float(u << 16);
  r.y = __uint_as_float(u & 0xffff0000u);
  return r;
}
__device__ inline unsigned int packbf(float a, float b) {
  return (unsigned int)f2bf(a) | ((unsigned int)f2bf(b) << 16);
}

// Direct global->LDS DMA, 16 B per lane. LDS dest = m0 (wave-uniform) +
// lane*16; global source is per-lane (this is how the swizzle is applied).
__device__ __forceinline__ void gload16(const U16* g, const U16* l) {
  unsigned int m0v =
      (unsigned int)__builtin_amdgcn_readfirstlane((int)(unsigned long long)l);
  asm volatile("s_mov_b32 m0, %0\n\t"
               "global_load_lds_dwordx4 %1, off"
               :
               : "s"(m0v), "v"(g)
               : "memory");
}

__device__ inline void ldcvt16(const float* p, U16* d) {
#pragma unroll
  for (int i = 0; i < 4; ++i) {
    float4 f = *(const float4*)(p + i * 4);
    d[i * 4 + 0] = f2bf(f.x); d[i * 4 + 1] = f2bf(f.y);
    d[i * 4 + 2] = f2bf(f.z); d[i * 4 + 3] = f2bf(f.w);
  }
}
__device__ inline void ldcvt16(const U16* p, U16* d) {
  uint4 a = *(const uint4*)p;
  uint4 b = *(const uint4*)(p + 8);
  *(uint4*)d = a;
  *(uint4*)(d + 8) = b;
}

// ---------------------------------------------------------------- fast path --
// prep: blocks [0,4096) = x fp32->bf16 conv (+rs zero);
//       blocks [4096,5120) = transp_w4 (z = (blk-4096)>>8):
//       z=0 Wq^T->WT; z=1 Wk^T->WT+WE; z=2 Wo^T->WoT; z=3 Wv conv->Wv16.
__global__ __launch_bounds__(256) void prep(
    const float* __restrict__ x, U16* __restrict__ x16, float* __restrict__ rs,
    const float* __restrict__ Wq, const float* __restrict__ Wk,
    const float* __restrict__ Wo, const float* __restrict__ Wv,
    U16* __restrict__ WT, U16* __restrict__ WoT, U16* __restrict__ Wv16) {
  __shared__ U16 tile[64][72];
  const int t = threadIdx.x;
  if (blockIdx.x < 4096) {  // conv
    int idx = blockIdx.x * 256 + t;
    if (idx < NB * SQ) rs[idx] = 0.f;
    int i = idx * 8;
    float4 a = *(const float4*)(x + i);
    float4 b = *(const float4*)(x + i + 4);
    uint4 w;
    w.x = packbf(a.x, a.y); w.y = packbf(a.z, a.w);
    w.z = packbf(b.x, b.y); w.w = packbf(b.z, b.w);
    *(uint4*)(x16 + i) = w;
    return;
  }
  const int tw = blockIdx.x - 4096;
  const int z = tw >> 8;
  const int rem = tw & 255;
  const int r0 = (rem >> 4) * 64, c0 = (rem & 15) * 64;
  const int tr = t >> 2, tc = (t & 3) * 16;
  if (z == 3) {  // straight conv of Wv
    U16 vals[16];
    ldcvt16(Wv + (size_t)(r0 + tr) * DM + c0 + tc, vals);
    U16* op = Wv16 + (size_t)(r0 + tr) * DM + c0 + tc;
    *(uint4*)op = *(uint4*)&vals[0];
    *(uint4*)(op + 8) = *(uint4*)&vals[8];
    return;
  }
  const float* src = (z == 0) ? Wq : (z == 1) ? Wk : Wo;
  U16* d = (z == 2) ? WoT : WT + (size_t)z * DM * DM;
  ldcvt16(src + (size_t)(r0 + tr) * DM + c0 + tc, &tile[tr][tc]);
  __syncthreads();
  U16 vals[16];
#pragma unroll
  for (int m = 0; m < 16; ++m) vals[m] = tile[tc + m][tr];
  U16* op = d + (size_t)(c0 + tr) * DM + r0 + tc;
  *(uint4*)op = *(uint4*)&vals[0];
  *(uint4*)(op + 8) = *(uint4*)&vals[8];
}

// transp_pack: grid (16, 32, 8), 256 thr.
//   z<4 : bf16 transpose of U batch z: [SQ][DM] -> [DM][SQ]
//   z>=4: pack_mask: 2048 blocks x 4 waves x 32 groups = 262144 u64 words.
__global__ __launch_bounds__(256) void transp_pack(
    const U16* __restrict__ src, U16* __restrict__ dst,
    const int* __restrict__ mask, U64* __restrict__ pm) {
  const int t = threadIdx.x;
  const int z = blockIdx.z;
  if (z >= 4) {
    const int tb = (z - 4) * 512 + blockIdx.y * 16 + blockIdx.x;  // 0..2047
    const int lane = t & 63;
    const int wv = tb * 4 + (t >> 6);
#pragma unroll 4
    for (int i = 0; i < 32; ++i) {
      size_t g = (size_t)wv * 32 + i;
      U64 b = __ballot(mask[g * 64 + lane] != 0);
      if (lane == 0) pm[g] = b;
    }
    return;
  }
  __shared__ U16 tile[64][72];
  const U16* s = src + (size_t)z * SQ * DM;
  U16* d = dst + (size_t)z * SQ * DM;
  const int r0 = blockIdx.y * 64, c0 = blockIdx.x * 64;
  const int tr = t >> 2, tc = (t & 3) * 16;
  ldcvt16(s + (size_t)(r0 + tr) * DM + c0 + tc, &tile[tr][tc]);
  __syncthreads();
  U16 vals[16];
#pragma unroll
  for (int m = 0; m < 16; ++m) vals[m] = tile[tc + m][tr];
  U16* op = d + (size_t)(c0 + tr) * SQ + r0 + tc;
  *(uint4*)op = *(uint4*)&vals[0];
  *(uint4*)(op + 8) = *(uint4*)&vals[8];
}

// ---- old 128x128 engine (kept for the small WvoT gemm only) ----------------
template <int EP>
__global__ __launch_bounds__(256) void gemm_mfma(
    const U16* __restrict__ A, const U16* __restrict__ B, void* __restrict__ Cv,
    int M, int N, int K, long long sA, long long sB, long long sC,
    const int* __restrict__ mask, float* __restrict__ rowsum, float scale) {
  __shared__ U16 As[128 * 72];
  __shared__ U16 Bs[128 * 72];
  const int t = threadIdx.x;
  const int lane = t & 63, wave = t >> 6;
  const int wm = wave >> 1, wn = wave & 1;
  const int q = lane >> 4, ln = lane & 15;
  const int z = blockIdx.z;
  const int m0 = blockIdx.y * 128, n0 = blockIdx.x * 128;
  A += (size_t)z * sA;
  B += (size_t)z * sB;

  f32x4 acc[4][4] = {};

  const int srow = t >> 3;
  const int scol = (t & 7) * 8;

  for (int k0 = 0; k0 < K; k0 += 64) {
    const U16* ga = A + (size_t)(m0 + srow) * K + k0 + scol;
    const U16* gb = B + (size_t)(n0 + srow) * K + k0 + scol;
#pragma unroll
    for (int it = 0; it < 4; ++it) {
      uint4 va = *(const uint4*)(ga + (size_t)it * 32 * K);
      uint4 vb = *(const uint4*)(gb + (size_t)it * 32 * K);
      *(uint4*)&As[(it * 32 + srow) * 72 + scol] = va;
      *(uint4*)&Bs[(it * 32 + srow) * 72 + scol] = vb;
    }
    __syncthreads();
#pragma unroll
    for (int kk = 0; kk < 64; kk += 32) {
      bhalf8 af[4], bg[4];
#pragma unroll
      for (int i = 0; i < 4; ++i) {
        af[i] = *(const bhalf8*)&As[(wm * 64 + i * 16 + ln) * 72 + kk + q * 8];
        bg[i] = *(const bhalf8*)&Bs[(wn * 64 + i * 16 + ln) * 72 + kk + q * 8];
      }
#pragma unroll
      for (int i = 0; i < 4; ++i)
#pragma unroll
        for (int j = 0; j < 4; ++j)
          acc[i][j] = __builtin_amdgcn_mfma_f32_16x16x32_bf16(af[i], bg[j], acc[i][j], 0, 0, 0);
    }
    __syncthreads();
  }

#pragma unroll
  for (int i = 0; i < 4; ++i) {
#pragma unroll
    for (int r = 0; r < 4; ++r) {
      const int rr = m0 + wm * 64 + i * 16 + q * 4 + r;
      float linv = 0.f;
      if constexpr (EP == 2) linv = 1.0f / (rowsum[(size_t)z * M + rr] + 1e-30f);
#pragma unroll
      for (int j = 0; j < 4; ++j) {
        const int c = n0 + wn * 64 + j * 16 + ln;
        float v = acc[i][j][r];
        if constexpr (EP == 0) {
          ((U16*)Cv)[(size_t)z * sC + (size_t)rr * N + c] = f2bf(v);
        } else {
          ((float*)Cv)[(size_t)z * sC + (size_t)rr * N + c] = v * linv;
        }
      }
    }
  }
}

// ---- R12 4-phase counted-vmcnt engine (QKU / score / PVout) ----------------
// C = A @ B'^T : A[M][K] bf16, B'[N][K] bf16, fp32 accum. BM=256, BK=64,
// 512 thr / 8 waves. WM=2 -> BN=256 (2Mx4N waves, per-wave 128x64, acc[8][4]);
// WM=4 -> BN=128 (4Mx2N waves, per-wave 64x64, acc[4][4]).
// LDS: Abuf[2][256*64] + Bbuf[2][BN*64]; phys-remapped contiguous slots:
// A phys = mh*128 + wm*(MR/2) + im*16 + ln; B phys = nh*HB + wn*32 + jn*16+ln.
// XOR-swizzle chunk^(physrow&7) on DMA *source* addr and ds_read addr.
// Per K-tile: 4 phases = C-quadrants (0,0),(0,1),(1,0),(1,1); stage plan:
// P0: BO[t+1], P1: AY[t+1], P2: AX[t+2], P3: BE[t+2].
// PUBLICATION RULE: vmcnt is per-wave; a slot is readable only after
// {all waves WAITV(N) covering it} + barrier, one phase earlier. Per-tile
// issue {b,2,2,b} makes N uniform = 4+2b at every phase. Never 0 in-loop.
// EP=1 (score): P = exp(mask(acc*scale)) via BIT-PACKED mask (u64/row-word,
// 16-lane broadcast) + fused rowsum atomics.
template <int EP, int WM>
__global__ __launch_bounds__(512, 1) void gemm8(
    const U16* __restrict__ A, const U16* __restrict__ B, void* __restrict__ Cv,
    int M, int N, int K, long long sA, long long sB, long long sC,
    const U64* __restrict__ pmask, float* __restrict__ rowsum, float scale) {
  constexpr int WN = 8 / WM;      // waves along N: 4 or 2
  constexpr int BN = WN * 64;     // 256 or 128
  constexpr int MR = 256 / WM;    // per-wave M rows: 128 or 64
  constexpr int FM = MR / 16;     // m-frags per wave: 8 or 4
  constexpr int IMq = FM / 2;     // m-frags per quadrant: 4 or 2
  constexpr int HB = BN / 2;      // B-half rows: 128 or 64
  constexpr int CB = HB / 64;     // stage calls per B-half: 2 or 1
  constexpr int VW = 4 + 2 * CB;  // uniform counted vmcnt (8 or 6)
  __shared__ __attribute__((aligned(16))) U16 Abuf[2][256 * 64];
  __shared__ __attribute__((aligned(16))) U16 Bbuf[2][BN * 64];
  const int t = threadIdx.x;
  const int lane = t & 63, wave = t >> 6;
  const int wm = wave / WN, wn = wave % WN;
  const int q = lane >> 4, ln = lane & 15;
  const int lxor = ln & 7;

  // T1: bijective chunked XCD swizzle (all grids used have nwg % 8 == 0).
  const int gx = gridDim.x, gy = gridDim.y;
  int lin = blockIdx.x + gx * (blockIdx.y + gy * blockIdx.z);
  const int cpx = (gx * gy * gridDim.z) >> 3;
  lin = (lin & 7) * cpx + (lin >> 3);
  const int bz = lin / (gx * gy);
  const int rem = lin - bz * gx * gy;
  const int by = rem / gx, bx = rem - by * gx;

  const int m0 = by * 256, n0 = bx * BN;
  const U16* Abase = A + (size_t)bz * sA + (size_t)m0 * K;
  const U16* Bbase = B + (size_t)bz * sB + (size_t)n0 * K;

  // staging geometry: each stage call covers 64 contiguous PHYS rows via
  // 8 waves x 8 rows; lane l -> phys row pr = wave*8 + (l>>3), phys chunk
  // (l&7). Source chunk is inverse-swizzled: (l&7) ^ (pr&7).
  const int pr = wave * 8 + (lane >> 3);
  const int cchunk = (((lane & 7) ^ ((lane >> 3) & 7)) << 3);
  int la[4];
#pragma unroll
  for (int c = 0; c < 4; ++c) {  // logical A row for phys chunk c
    int p = c * 64 + pr;
    int mh = p >> 7, q64 = p & 127;
    la[c] = (q64 / (MR / 2)) * MR + mh * (MR / 2) + (q64 % (MR / 2));
  }
  int lb[4] = {0, 0, 0, 0};
#pragma unroll
  for (int c = 0; c < 2 * CB; ++c) {  // logical B row for phys chunk c
    int p = c * 64 + pr;
    int nh = p / HB, rem2 = p % HB;
    lb[c] = (rem2 >> 5) * 64 + nh * 32 + (rem2 & 31);
  }
  const U16* gA0 = Abase + (size_t)la[0] * K + cchunk;
  const U16* gA1 = Abase + (size_t)la[1] * K + cchunk;
  const U16* gA2 = Abase + (size_t)la[2] * K + cchunk;
  const U16* gA3 = Abase + (size_t)la[3] * K + cchunk;
  const U16* gB0 = Bbase + (size_t)lb[0] * K + cchunk;
  const U16* gB1 = (CB == 2) ? Bbase + (size_t)lb[1] * K + cchunk : gB0;
  const U16* gB2 = Bbase + (size_t)lb[CB] * K + cchunk;
  const U16* gB3 = (CB == 2) ? Bbase + (size_t)lb[3] * K + cchunk : gB2;
  const int wofs = wave * 8 * 64;  // wave's LDS offset within a 64-row call

#define ST_AX(bi, ko) { gload16(gA0 + (ko), &Abuf[bi][0 * 64 + wofs]);         \
                        gload16(gA1 + (ko), &Abuf[bi][64 * 64 + wofs]); }
#define ST_AY(bi, ko) { gload16(gA2 + (ko), &Abuf[bi][128 * 64 + wofs]);       \
                        gload16(gA3 + (ko), &Abuf[bi][192 * 64 + wofs]); }
#define ST_BE(bi, ko) { gload16(gB0 + (ko), &Bbuf[bi][0 * 64 + wofs]);         \
                        if (CB == 2) gload16(gB1 + (ko), &Bbuf[bi][64 * 64 + wofs]); }
#define ST_BO(bi, ko) { gload16(gB2 + (ko), &Bbuf[bi][HB * 64 + wofs]);        \
                        if (CB == 2) gload16(gB3 + (ko), &Bbuf[bi][(HB + 64) * 64 + wofs]); }

  f32x4 acc[FM][4] = {};
  bhalf8 af[IMq][2], bgE[2][2], bgO[2][2];

#define LDA(bi, mh) {                                                          \
  _Pragma("unroll") for (int im = 0; im < IMq; ++im)                           \
  _Pragma("unroll") for (int kx = 0; kx < 2; ++kx)                             \
    af[im][kx] = *(const bhalf8*)&Abuf[bi][                                    \
        ((mh) * 128 + wm * (MR / 2) + im * 16 + ln) * 64 +                     \
        (((kx * 4 + q) ^ lxor) << 3)]; }
#define LDB(bi, nh, BG) {                                                      \
  _Pragma("unroll") for (int jn = 0; jn < 2; ++jn)                             \
  _Pragma("unroll") for (int kx = 0; kx < 2; ++kx)                             \
    BG[jn][kx] = *(const bhalf8*)&Bbuf[bi][                                    \
        ((nh) * HB + wn * 32 + jn * 16 + ln) * 64 +                            \
        (((kx * 4 + q) ^ lxor) << 3)]; }
#define MQ(mh, nh, BG) {                                                       \
  __builtin_amdgcn_s_setprio(1);                                               \
  _Pragma("unroll") for (int im = 0; im < IMq; ++im)                           \
  _Pragma("unroll") for (int jn = 0; jn < 2; ++jn)                             \
  _Pragma("unroll") for (int kx = 0; kx < 2; ++kx)                             \
    acc[(mh) * IMq + im][(nh) * 2 + jn] =                                      \
        __builtin_amdgcn_mfma_f32_16x16x32_bf16(                               \
            af[im][kx], BG[jn][kx], acc[(mh) * IMq + im][(nh) * 2 + jn],       \
            0, 0, 0);                                                          \
  __builtin_amdgcn_s_setprio(0); }
#define WAITV(n) asm volatile("s_waitcnt vmcnt(%0)" :: "i"(n) : "memory")
#define BAR() __builtin_amdgcn_s_barrier()
#define LGKM0() asm volatile("s_waitcnt lgkmcnt(0)" ::: "memory")

#define TILE8(bi, nbi, kA, kB)                                                 \
  {                                                                            \
    ST_BO(nbi, kA); WAITV(VW);                                                 \
    LDA(bi, 0); LDB(bi, 0, bgE);                                               \
    BAR(); LGKM0(); MQ(0, 0, bgE); BAR();                                      \
    ST_AY(nbi, kA); WAITV(VW);                                                 \
    LDB(bi, 1, bgO);                                                           \
    BAR(); LGKM0(); MQ(0, 1, bgO); BAR();                                      \
    ST_AX(bi, kB); WAITV(VW);                                                  \
    LDA(bi, 1);                                                                \
    BAR(); LGKM0(); MQ(1, 0, bgE); BAR();                                      \
    ST_BE(bi, kB); WAITV(VW);                                                  \
    BAR(); LGKM0(); MQ(1, 1, bgO); BAR();                                      \
  }

  const int NT = K >> 6;  // even (>= 16) for all shapes used here
  // prologue: AX[0], BE[0], BO[0], AY[0], AX[1], BE[1]; publish AX[0]/BE[0]
  // (oldest 2+b loads) via WAITV(VW)+BAR.
  ST_AX(0, 0); ST_BE(0, 0); ST_BO(0, 0); ST_AY(0, 0);
  ST_AX(1, 64); ST_BE(1, 64);
  WAITV(VW); BAR();
  for (int tt = 0; tt < NT; tt += 2) {
    const int k1 = (tt + 1) * 64;                      // tile tt+1 (valid)
    const int k2 = (tt + 2 < NT) ? (tt + 2) * 64 : 0;  // tile tt+2 (clamped)
    const int k3 = (tt + 3 < NT) ? (tt + 3) * 64 : 0;  // tile tt+3 (clamped)
    TILE8(0, 1, k1, k2);
    TILE8(1, 0, k2, k3);
  }
  WAITV(0);

#undef ST_AX
#undef ST_AY
#undef ST_BE
#undef ST_BO
#undef LDA
#undef LDB
#undef MQ
#undef WAITV
#undef BAR
#undef LGKM0
#undef TILE8

  // epilogue
#pragma unroll
  for (int i = 0; i < FM; ++i) {
#pragma unroll
    for (int r = 0; r < 4; ++r) {
      const int rr = m0 + wm * MR + i * 16 + q * 4 + r;
      float linv = 0.f;
      if constexpr (EP == 2) linv = 1.0f / (rowsum[(size_t)bz * M + rr] + 1e-30f);
      U64 m64 = 0;
      if constexpr (EP == 1)
        m64 = pmask[((size_t)bz * M + rr) * (N >> 6) + (n0 >> 6) + wn];
      float psum = 0.f;
#pragma unroll
      for (int j = 0; j < 4; ++j) {
        const int c = n0 + wn * 64 + j * 16 + ln;
        float v = acc[i][j][r];
        if constexpr (EP == 0) {
          ((U16*)Cv)[(size_t)bz * sC + (size_t)rr * N + c] = f2bf(v);
        } else if constexpr (EP == 1) {
          int mk = (int)((m64 >> (j * 16 + ln)) & 1ull);
          float p = mk ? __expf(v * scale) : 0.f;
          U16 pb = f2bf(p);
          ((U16*)Cv)[(size_t)bz * sC + (size_t)rr * N + c] = pb;
          psum += __uint_as_float((unsigned int)pb << 16);  // sum rounded P
        } else {
          ((float*)Cv)[(size_t)bz * sC + (size_t)rr * N + c] = v * linv;
        }
      }
      if constexpr (EP == 1) {
#pragma unroll
        for (int off = 8; off > 0; off >>= 1) psum += __shfl_xor(psum, off, 64);
        if (ln == 0) atomicAdd(&rowsum[(size_t)bz * M + rr], psum);
      }
    }
  }
}

// ------------------------------------------------------------ fallback path --
__device__ inline float4 load4(const float* p) { return *(const float4*)p; }
__device__ inline float4 load4(const U16* p) {
  uint2 w = *(const uint2*)p;
  float2 f0 = bfp2(w.x), f1 = bfp2(w.y);
  return make_float4(f0.x, f0.y, f1.x, f1.y);
}
__device__ inline void store4(float* p, float a, float b, float c, float d) {
  *(float4*)p = make_float4(a, b, c, d);
}
__device__ inline void store4(U16* p, float a, float b, float c, float d) {
  uint2 w;
  w.x = packbf(a, b);
  w.y = packbf(c, d);
  *(uint2*)p = w;
}
template <typename TA, typename TB, typename TC>
__global__ __launch_bounds__(256) void gemm_t(
    const TA* __restrict__ A, const TB* __restrict__ B,
    TC* __restrict__ C, int M, int N, int K) {
  __shared__ float As[16][64];
  __shared__ float Bs[16][64];
  const int t = threadIdx.x;
  const int tx = t & 15, ty = t >> 4;
  const int m0 = blockIdx.y * 64;
  const int n0 = blockIdx.x * 64;
  const int arow = t >> 2, akq = (t & 3) * 4;
  const int brow = t >> 4, bcg = (t & 15) * 4;
  float acc[4][4] = {};
  for (int k0 = 0; k0 < K; k0 += 16) {
    {
      float4 f = load4(A + (size_t)(m0 + arow) * K + k0 + akq);
      As[akq + 0][arow] = f.x; As[akq + 1][arow] = f.y;
      As[akq + 2][arow] = f.z; As[akq + 3][arow] = f.w;
    }
    {
      float4 f = load4(B + (size_t)(k0 + brow) * N + n0 + bcg);
      *(float4*)&Bs[brow][bcg] = f;
    }
    __syncthreads();
#pragma unroll
    for (int kk = 0; kk < 16; ++kk) {
      float4 a = *(const float4*)&As[kk][ty * 4];
      float4 b = *(const float4*)&Bs[kk][tx * 4];
      float av[4] = {a.x, a.y, a.z, a.w};
      float bv[4] = {b.x, b.y, b.z, b.w};
#pragma unroll
      for (int i = 0; i < 4; ++i)
#pragma unroll
        for (int j = 0; j < 4; ++j) acc[i][j] += av[i] * bv[j];
    }
    __syncthreads();
  }
#pragma unroll
  for (int i = 0; i < 4; ++i)
    store4(&C[(size_t)(m0 + ty * 4 + i) * N + n0 + tx * 4],
           acc[i][0], acc[i][1], acc[i][2], acc[i][3]);
}
__global__ __launch_bounds__(256) void flash_wave(
    const U16* __restrict__ Q, const U16* __restrict__ Kd,
    const U16* __restrict__ V, const int* __restrict__ mask,
    U16* __restrict__ O) {
  __shared__ float q_s[4][DM];
  const int t = threadIdx.x;
  const int w = t >> 6;
  const int lane = t & 63;
  const int row = blockIdx.x * 4 + w;
  const int b = row >> 11;
  const size_t bo = (size_t)b * SQ * DM;
  const size_t mrow0 = (size_t)row * SQ;
  {
    const U16* qp = Q + (size_t)row * DM + lane * 16;
    uint4 w0 = *(const uint4*)qp;
    uint4 w1 = *(const uint4*)(qp + 8);
    float* dst = &q_s[w][lane * 16];
    float2 f;
    f = bfp2(w0.x); dst[0] = f.x;  dst[1] = f.y;
    f = bfp2(w0.y); dst[2] = f.x;  dst[3] = f.y;
    f = bfp2(w0.z); dst[4] = f.x;  dst[5] = f.y;
    f = bfp2(w0.w); dst[6] = f.x;  dst[7] = f.y;
    f = bfp2(w1.x); dst[8] = f.x;  dst[9] = f.y;
    f = bfp2(w1.y); dst[10] = f.x; dst[11] = f.y;
    f = bfp2(w1.z); dst[12] = f.x; dst[13] = f.y;
    f = bfp2(w1.w); dst[14] = f.x; dst[15] = f.y;
  }
  __syncthreads();
  float m = -3.0e38f, l = 0.f;
  float o[16] = {};
  const int dbase = lane * 16;
  const float* qrow = q_s[w];
  for (int j0 = 0; j0 < SQ; j0 += 64) {
    float s;
    {
      const U16* kp = Kd + bo + (size_t)(j0 + lane) * DM;
      float acc = 0.f;
      for (int d = 0; d < DM; d += 8) {
        uint4 kw = *(const uint4*)(kp + d);
        float2 a0 = bfp2(kw.x), a1 = bfp2(kw.y), a2 = bfp2(kw.z), a3 = bfp2(kw.w);
        acc += qrow[d] * a0.x + qrow[d + 1] * a0.y + qrow[d + 2] * a1.x +
               qrow[d + 3] * a1.y + qrow[d + 4] * a2.x + qrow[d + 5] * a2.y +
               qrow[d + 6] * a3.x + qrow[d + 7] * a3.y;
      }
      s = acc * 0.03125f;
      if (mask[mrow0 + j0 + lane] == 0) s = -1e10f;
    }
    float ms = s;
#pragma unroll
    for (int off = 32; off > 0; off >>= 1) ms = fmaxf(ms, __shfl_xor(ms, off, 64));
    float mn = fmaxf(m, ms);
    float alpha = __expf(m - mn);
    float p = __expf(s - mn);
    float ps = p;
#pragma unroll
    for (int off = 32; off > 0; off >>= 1) ps += __shfl_xor(ps, off, 64);
    l = l * alpha + ps;
    m = mn;
#pragma unroll
    for (int k = 0; k < 16; ++k) o[k] *= alpha;
    const U16* vp = V + bo + (size_t)j0 * DM + dbase;
    for (int j = 0; j < 64; ++j) {
      float pj = __shfl(p, j, 64);
      uint4 v0 = *(const uint4*)(vp + (size_t)j * DM);
      uint4 v1 = *(const uint4*)(vp + (size_t)j * DM + 8);
      float2 f0 = bfp2(v0.x), f1 = bfp2(v0.y), f2 = bfp2(v0.z), f3 = bfp2(v0.w);
      float2 g0 = bfp2(v1.x), g1 = bfp2(v1.y), g2 = bfp2(v1.z), g3 = bfp2(v1.w);
      o[0] += pj * f0.x;  o[1] += pj * f0.y;  o[2] += pj * f1.x;  o[3] += pj * f1.y;
      o[4] += pj * f2.x;  o[5] += pj * f2.y;  o[6] += pj * f3.x;  o[7] += pj * f3.y;
      o[8] += pj * g0.x;  o[9] += pj * g0.y;  o[10] += pj * g1.x; o[11] += pj * g1.y;
      o[12] += pj * g2.x; o[13] += pj * g2.y; o[14] += pj * g3.x; o[15] += pj * g3.y;
    }
  }
  float linv = (l > 0.f) ? (1.0f / l) : 0.f;
  U16* op = O + (size_t)row * DM + dbase;
  uint4 r0, r1;
  r0.x = packbf(o[0] * linv, o[1] * linv);
  r0.y = packbf(o[2] * linv, o[3] * linv);
  r0.z = packbf(o[4] * linv, o[5] * linv);
  r0.w = packbf(o[6] * linv, o[7] * linv);
  r1.x = packbf(o[8] * linv, o[9] * linv);
  r1.y = packbf(o[10] * linv, o[11] * linv);
  r1.z = packbf(o[12] * linv, o[13] * linv);
  r1.w = packbf(o[14] * linv, o[15] * linv);
  *(uint4*)op = r0;
  *(uint4*)(op + 8) = r1;
}

extern "C" void kernel_launch(void* const* d_in, const int* in_sizes, int n_in,
                              void* d_out, int out_size, void* d_ws, size_t ws_size,
                              hipStream_t stream) {
  const float* x  = (const float*)d_in[0];
  const int* mask = (const int*)d_in[1];
  const float* Wq = (const float*)d_in[2];
  const float* Wk = (const float*)d_in[3];
  const float* Wv = (const float*)d_in[4];
  const float* Wo = (const float*)d_in[5];
  float* out = (float*)d_out;

  const size_t MB = 1u << 20;
  const size_t E = (size_t)NB * SQ * DM;  // 8388608
  const size_t WE = (size_t)DM * DM;      // 1048576

  if (ws_size >= 121 * MB) {
    // -------- fast MFMA path (6 dispatches) --------
    char* ws = (char*)d_ws;
    U16* WT   = (U16*)ws;               // slot0 Wq^T, slot1 Wk^T, slot2 Wvo^T
    U16* WoT  = (U16*)(ws + 6 * MB);    // Wo^T (2 MiB; becomes pmask after WvoT gemm)
    U64* pm   = (U64*)(ws + 6 * MB);    // bit-packed mask (2 MiB)
    U16* x16  = (U16*)(ws + 8 * MB);
    U16* Q16  = (U16*)(ws + 24 * MB);   // Q,K,U contiguous at stride E elems
    U16* K16  = (U16*)(ws + 40 * MB);
    U16* U16b = (U16*)(ws + 56 * MB);   // U = x @ (Wv Wo) = V Wo
    U16* Wv16 = (U16*)(ws + 72 * MB);   // Wv bf16 (2 MiB, dead after WvoT gemm)
    U16* UT16 = (U16*)(ws + 72 * MB);   // U^T per batch (16 MiB, written later)
    U16* P16  = (U16*)(ws + 88 * MB);   // 32 MiB
    float* rs = (float*)(ws + 120 * MB);

    // 1: conv + transp_w4 merged (256-thr streaming).
    prep<<<dim3(5120), 256, 0, stream>>>(x, x16, rs, Wq, Wk, Wo, Wv, WT, WoT, Wv16);

    // 2: Wvo^T[e][d] = sum_f WoT[e][f] * Wv[d][f]  (2.1 GF, 64 wgs).
    gemm_mfma<0><<<dim3(DM / 128, DM / 128, 1), 256, 0, stream>>>(
        WoT, Wv16, WT + 2 * WE, DM, DM, DM, 0, 0, 0, nullptr, nullptr, 0.f);

    // 3: fused Q/K/U: z in {0,1,2} -> WqT/WkT/WvoT, writes Q16/K16/U16b.
    //    WM=4 (BN=128): grid 8*32*3 = 768 wgs -> 3 exact full-chip waves.
    gemm8<0, 4><<<dim3(DM / 128, (NB * SQ) / 256, 3), 512, 0, stream>>>(
        x16, WT, Q16, NB * SQ, DM, DM,
        0, (long long)WE, (long long)E, nullptr, nullptr, 0.f);

    // 4: transp-U + pack_mask merged (256-thr streaming; pm -> dead WoT slot).
    transp_pack<<<dim3(16, 32, 8), 256, 0, stream>>>(U16b, UT16, mask, pm);

    // 5: score P = exp(mask(Q@K^T/32)) + rowsum atomics.
    //    WM=2 (BN=256): grid 8*8*4 = 256 wgs -> exactly 1 wg/CU.
    gemm8<1, 2><<<dim3(SQ / 256, SQ / 256, NB), 512, 0, stream>>>(
        Q16, K16, P16, SQ, SQ, DM,
        (long long)SQ * DM, (long long)SQ * DM, (long long)SQ * SQ,
        pm, rs, 0.03125f);

    // 6: out = (P @ UT^T) / rowsum, fp32 direct to d_out.
    gemm8<2, 4><<<dim3(DM / 128, SQ / 256, NB), 512, 0, stream>>>(
        P16, UT16, out, SQ, DM, SQ,
        (long long)SQ * SQ, (long long)DM * SQ, (long long)SQ * DM,
        nullptr, rs, 0.f);
  } else {
    // -------- round-4 proven fallback (48 MB) --------
    U16* Kw = (U16*)d_ws;
    U16* Vw = Kw + E;
    U16* Qw = Vw + E;
    U16* Ow = Qw;
    dim3 blk(256);
    dim3 gg(DM / 64, (NB * SQ) / 64);
    gemm_t<float, float, U16><<<gg, blk, 0, stream>>>(x, Wk, Kw, NB * SQ, DM, DM);
    gemm_t<float, float, U16><<<gg, blk, 0, stream>>>(x, Wv, Vw, NB * SQ, DM, DM);
    gemm_t<float, float, U16><<<gg, blk, 0, stream>>>(x, Wq, Qw, NB * SQ, DM, DM);
    flash_wave<<<dim3((NB * SQ) / 4), blk, 0, stream>>>(Qw, Kw, Vw, mask, Ow);
    gemm_t<U16, float, float><<<gg, blk, 0, stream>>>(Ow, Wo, out, NB * SQ, DM, DM);
  }
}